// Round 10
// baseline (239.189 us; speedup 1.0000x reference)
//
#include <hip/hip_runtime.h>

#define D       32
#define BS      256
#define CBLK    500          // edge-chunk blocks for the local-sort pass
#define MAXBUCK 2048         // LDS histogram capacity (NBUCK = ceil(N/64) must fit)
#define MAX_EPT 13           // max edges per thread in local sort (ceil(EPB/BS))
#define ECAP    4096         // LDS edge-buffer capacity in k_merge (bucket size)
#define POISON_BASE ((int)0xAAAAAAAAu)

// ======== pass 1: block-local counting sort (+ fused layer-1 GEMM) ========
// sort blocks [0,CBLK): bucket = dst>>6; write own contiguous staging slice.
// stash packs (bucket<<19 | local<<13 | rank) so loop 2 never re-reads dst.
// staged payload: (src | local<<17, w_bits)
__global__ void k_localsort_gemm(const int* __restrict__ dst, const int* __restrict__ src,
                                 const float* __restrict__ w, int* __restrict__ bc,
                                 int* __restrict__ locoff, int2* __restrict__ staged,
                                 int E, int EPB, int NBUCK,
                                 const float* __restrict__ X, const float* __restrict__ Wm,
                                 float* __restrict__ H, int n) {
    __shared__ int    bins[MAXBUCK];
    __shared__ int    sscan[BS];
    __shared__ int    carry;
    __shared__ float4 Ws[D * 8];
    int t = threadIdx.x;

    if ((int)blockIdx.x >= CBLK) {
        // ---- gemm1: H = X @ W1 (8 lanes/node, float4) ----
        for (int i = t; i < D * 8; i += BS) Ws[i] = ((const float4*)Wm)[i];
        __syncthreads();
        int gid  = (blockIdx.x - CBLK) * BS + t;
        int node = gid >> 3;
        int q    = gid & 7;
        if (node >= n) return;
        float4 xv  = ((const float4*)X)[node * 8 + q];
        float4 acc = make_float4(0.f, 0.f, 0.f, 0.f);
#pragma unroll
        for (int k = 0; k < D; ++k) {
            float comp = (k & 3) == 0 ? xv.x : (k & 3) == 1 ? xv.y
                       : (k & 3) == 2 ? xv.z : xv.w;
            float  xk = __shfl(comp, k >> 2, 8);
            float4 wr = Ws[k * 8 + q];
            acc.x += xk * wr.x; acc.y += xk * wr.y;
            acc.z += xk * wr.z; acc.w += xk * wr.w;
        }
        ((float4*)H)[node * 8 + q] = acc;
        return;
    }

    int blk = blockIdx.x;
    int beg = blk * EPB;
    int end = min(E, beg + EPB);
    for (int i = t; i < NBUCK; i += BS) bins[i] = 0;
    __syncthreads();

    // loop 1: histogram; stash (bucket<<19 | local<<13 | rank)
    int stash[MAX_EPT];
#pragma unroll
    for (int i = 0; i < MAX_EPT; ++i) {
        int e = beg + i * BS + t;
        stash[i] = -1;
        if (e < end) {
            int dv = dst[e];
            int b  = dv >> 6;
            int r  = atomicAdd(&bins[b], 1);        // LDS atomic; r < EPB <= 8192
            stash[i] = (b << 19) | ((dv & 63) << 13) | r;
        }
    }
    __syncthreads();
    // counts out (before scan overwrites bins)
    for (int i = t; i < NBUCK; i += BS) bc[i * CBLK + blk] = bins[i];
    __syncthreads();
    // chunked exclusive scan of bins in place
    if (t == 0) carry = 0;
    __syncthreads();
    for (int base = 0; base < NBUCK; base += BS) {
        int idx = base + t;
        int v = (idx < NBUCK) ? bins[idx] : 0;
        sscan[t] = v;
        __syncthreads();
        for (int off = 1; off < BS; off <<= 1) {
            int u = (t >= off) ? sscan[t - off] : 0;
            __syncthreads();
            sscan[t] += u;
            __syncthreads();
        }
        if (idx < NBUCK) bins[idx] = carry + sscan[t] - v;
        __syncthreads();
        if (t == 0) carry += sscan[BS - 1];
        __syncthreads();
    }
    for (int i = t; i < NBUCK; i += BS) locoff[i * CBLK + blk] = bins[i];
    __syncthreads();

    // loop 2: place edges into own staging slice (writes confined to EPB*8 bytes)
    int2* myslice = staged + (size_t)blk * EPB;
#pragma unroll
    for (int i = 0; i < MAX_EPT; ++i) {
        if (stash[i] >= 0) {
            int e     = beg + i * BS + t;
            int b     = stash[i] >> 19;
            int local = (stash[i] >> 13) & 63;
            int r     = stash[i] & 0x1FFF;
            int pos   = bins[b] + r;
            myslice[pos] = make_int2(src[e] | (local << 17), __float_as_int(w[e]));
        }
    }
}

// ======== scans over the (bucket-major) count table ========
__global__ void k_scanA(const int* __restrict__ bc, int* __restrict__ asum, int m) {
    __shared__ int s[BS];
    int t = threadIdx.x, i = blockIdx.x * BS + t;
    s[t] = (i < m) ? bc[i] : 0;
    __syncthreads();
    for (int off = BS / 2; off > 0; off >>= 1) {
        if (t < off) s[t] += s[t + off];
        __syncthreads();
    }
    if (t == 0) asum[blockIdx.x] = s[0];
}

__global__ void k_scanB(const int* __restrict__ asum, int* __restrict__ aex, int m) {
    __shared__ int s[BS];
    __shared__ int carry;
    int t = threadIdx.x;
    if (t == 0) carry = 0;
    __syncthreads();
    for (int base = 0; base < m; base += BS) {
        int i = base + t;
        int v = (i < m) ? asum[i] : 0;
        s[t] = v;
        __syncthreads();
        for (int off = 1; off < BS; off <<= 1) {
            int u = (t >= off) ? s[t - off] : 0;
            __syncthreads();
            s[t] += u;
            __syncthreads();
        }
        if (i < m) aex[i] = carry + s[t] - v;
        __syncthreads();
        if (t == BS - 1) carry += s[BS - 1];
        __syncthreads();
    }
}

__global__ void k_scanC(int* __restrict__ bc, const int* __restrict__ aex, int m) {
    __shared__ int s[BS];
    int t = threadIdx.x, i = blockIdx.x * BS + t;
    int v = (i < m) ? bc[i] : 0;
    s[t] = v;
    __syncthreads();
    for (int off = 1; off < BS; off <<= 1) {
        int u = (t >= off) ? s[t - off] : 0;
        __syncthreads();
        s[t] += u;
        __syncthreads();
    }
    if (i < m) bc[i] = aex[blockIdx.x] + s[t] - v;   // -> global positions sc[]
}

// ======== pass 3: per-bucket merge -> fine CSR + dinv + emeta ========
__global__ void k_merge(const int* __restrict__ sc, const int* __restrict__ locoff,
                        const int2* __restrict__ staged, int2* __restrict__ emeta,
                        int* __restrict__ rowptr, float* __restrict__ dinv,
                        int N, int E, int NBUCK, int EPB, int M) {
    __shared__ int2  ebuf[ECAP];
    __shared__ int   ihist[64];
    __shared__ float fdeg[64];
    __shared__ int   cursor[64];
    __shared__ int   fitsf;
    int b = blockIdx.x, t = threadIdx.x;
    int bstart = sc[b * CBLK];
    int bend   = (b == NBUCK - 1) ? E : sc[(b + 1) * CBLK];
    if (t < 64) { ihist[t] = 0; fdeg[t] = 0.0f; }
    if (t == 0) fitsf = (bend - bstart) <= ECAP;
    __syncthreads();
    bool fits = fitsf;

    for (int rr = t; rr < CBLK; rr += BS) {
        int cell = b * CBLK + rr;
        int gs = sc[cell];
        int ge = (cell + 1 < M) ? sc[cell + 1] : E;
        int ls = locoff[cell];
        const int2* run = staged + (size_t)rr * EPB + ls;
        for (int j = 0; j < ge - gs; ++j) {
            int2 v = run[j];
            int local = (v.x >> 17) & 63;
            atomicAdd(&ihist[local], 1);
            atomicAdd(&fdeg[local], __int_as_float(v.y));
            if (fits) ebuf[gs - bstart + j] = v;
        }
    }
    __syncthreads();
    if (t < 64) {                        // wave 0: 64-lane scan of node bins
        int v = ihist[t];
        int incl = v;
#pragma unroll
        for (int off = 1; off < 64; off <<= 1) {
            int u = __shfl_up(incl, off, 64);
            if (t >= off) incl += u;
        }
        int excl = incl - v;
        int node = b * 64 + t;
        if (node < N) {
            rowptr[node] = bstart + excl;
            dinv[node]   = rsqrtf(2.0f + fdeg[t]);
        }
        if (b == NBUCK - 1 && t == 0) rowptr[N] = E;
        cursor[t] = excl;
    }
    __syncthreads();
    for (int rr = t; rr < CBLK; rr += BS) {
        int cell = b * CBLK + rr;
        int gs = sc[cell];
        int ge = (cell + 1 < M) ? sc[cell + 1] : E;
        int ls = locoff[cell];
        const int2* run = staged + (size_t)rr * EPB + ls;
        for (int j = 0; j < ge - gs; ++j) {
            int2 v = fits ? ebuf[gs - bstart + j] : run[j];
            int local = (v.x >> 17) & 63;
            int r = atomicAdd(&cursor[local], 1);
            emeta[bstart + r] = make_int2(v.x & 0x1FFFF, v.y);
        }
    }
}

// ======== layers ========
__global__ void k_gemm(const float* __restrict__ X, const float* __restrict__ W,
                       float* __restrict__ H, int n) {
    __shared__ float4 Ws[D * 8];
    int tid = threadIdx.x;
    for (int i = tid; i < D * 8; i += blockDim.x) Ws[i] = ((const float4*)W)[i];
    __syncthreads();
    int gid  = blockIdx.x * blockDim.x + tid;
    int node = gid >> 3;
    int q    = gid & 7;
    if (node >= n) return;
    float4 xv  = ((const float4*)X)[node * 8 + q];
    float4 acc = make_float4(0.f, 0.f, 0.f, 0.f);
#pragma unroll
    for (int k = 0; k < D; ++k) {
        float comp = (k & 3) == 0 ? xv.x : (k & 3) == 1 ? xv.y
                   : (k & 3) == 2 ? xv.z : xv.w;
        float  xk = __shfl(comp, k >> 2, 8);
        float4 wr = Ws[k * 8 + q];
        acc.x += xk * wr.x; acc.y += xk * wr.y;
        acc.z += xk * wr.z; acc.w += xk * wr.w;
    }
    ((float4*)H)[node * 8 + q] = acc;
}

// NORM_STORE: emeta.y holds raw w -> compute nm = dinv[s]*w*dinv[d], persist it.
// FUSE_GEMM: out = relu(agg_row) @ W2 (written to 16B-ALIGNED buffer)
template <bool NORM_STORE, bool FUSE_GEMM>
__global__ void k_aggregate(const int* __restrict__ rowptr, int2* __restrict__ emeta,
                            const float* __restrict__ H, const float* __restrict__ dinv,
                            const float* __restrict__ b, const float* __restrict__ W2,
                            float* __restrict__ out, int n) {
    __shared__ float4 Ws[D * 8];
    int tid = threadIdx.x;
    if (FUSE_GEMM) {
        for (int i = tid; i < D * 8; i += BS) Ws[i] = ((const float4*)W2)[i];
        __syncthreads();
    }

    int gid  = blockIdx.x * BS + tid;
    int node = gid >> 3;
    int q    = gid & 7;
    if (node >= n) return;

    const float4* H4 = (const float4*)H;
    float  di = dinv[node];
    float  s2 = 2.0f * di * di;
    float4 bq = ((const float4*)b)[q];
    float4 h0 = H4[node * 8 + q];
    float4 acc = make_float4(h0.x * s2 + bq.x, h0.y * s2 + bq.y,
                             h0.z * s2 + bq.z, h0.w * s2 + bq.w);

    int beg  = rowptr[node];
    int end  = rowptr[node + 1];
    int full = beg + ((end - beg) & ~7);

    for (int i0 = beg; i0 < full; i0 += 8) {
        int  idx = i0 + q;
        int2 em  = emeta[idx];
        float nm;
        if (NORM_STORE) {
            nm = dinv[em.x] * __int_as_float(em.y) * di;
            emeta[idx].y = __float_as_int(nm);
        } else {
            nm = __int_as_float(em.y);
        }
#pragma unroll
        for (int j = 0; j < 8; ++j) {
            int    s   = __shfl(em.x, j, 8);
            float  nmj = __shfl(nm, j, 8);
            float4 hv  = H4[s * 8 + q];
            acc.x += nmj * hv.x; acc.y += nmj * hv.y;
            acc.z += nmj * hv.z; acc.w += nmj * hv.w;
        }
    }
    if (full < end) {
        int  idx = full + q;
        bool ok  = idx < end;
        int2 em  = ok ? emeta[idx] : make_int2(0, 0);
        float nm;
        if (NORM_STORE) {
            nm = ok ? dinv[em.x] * __int_as_float(em.y) * di : 0.0f;
            if (ok) emeta[idx].y = __float_as_int(nm);
        } else {
            nm = __int_as_float(em.y);
        }
        int rem = end - full;
        for (int j = 0; j < rem; ++j) {
            int    s   = __shfl(em.x, j, 8);
            float  nmj = __shfl(nm, j, 8);
            float4 hv  = H4[s * 8 + q];
            acc.x += nmj * hv.x; acc.y += nmj * hv.y;
            acc.z += nmj * hv.z; acc.w += nmj * hv.w;
        }
    }
    acc.x = fmaxf(acc.x, 0.f); acc.y = fmaxf(acc.y, 0.f);
    acc.z = fmaxf(acc.z, 0.f); acc.w = fmaxf(acc.w, 0.f);

    if (FUSE_GEMM) {
        float4 o = make_float4(0.f, 0.f, 0.f, 0.f);
#pragma unroll
        for (int k = 0; k < D; ++k) {
            float comp = (k & 3) == 0 ? acc.x : (k & 3) == 1 ? acc.y
                       : (k & 3) == 2 ? acc.z : acc.w;
            float  hk = __shfl(comp, k >> 2, 8);
            float4 wr = Ws[k * 8 + q];
            o.x += hk * wr.x; o.y += hk * wr.y;
            o.z += hk * wr.z; o.w += hk * wr.w;
        }
        ((float4*)out)[node * 8 + q] = o;
    } else {
        ((float4*)out)[node * 8 + q] = acc;
    }
}

// ======== fallback path (round-5 proven, global-atomic hist) ========
__global__ void k_hist_gemm(const int4* __restrict__ dst4, int* __restrict__ cnt,
                            int4* __restrict__ rank4, int E4,
                            const float* __restrict__ X, const float* __restrict__ W,
                            float* __restrict__ H, int n, int gE4) {
    __shared__ float4 Ws[D * 8];
    int tid = threadIdx.x;
    if ((int)blockIdx.x < gE4) {
        int i = blockIdx.x * BS + tid;
        if (i >= E4) return;
        int4 d = dst4[i];
        int4 r;
        r.x = atomicAdd(&cnt[d.x], 1) - POISON_BASE;
        r.y = atomicAdd(&cnt[d.y], 1) - POISON_BASE;
        r.z = atomicAdd(&cnt[d.z], 1) - POISON_BASE;
        r.w = atomicAdd(&cnt[d.w], 1) - POISON_BASE;
        rank4[i] = r;
        return;
    }
    for (int i = tid; i < D * 8; i += BS) Ws[i] = ((const float4*)W)[i];
    __syncthreads();
    int gid  = (blockIdx.x - gE4) * BS + tid;
    int node = gid >> 3;
    int q    = gid & 7;
    if (node >= n) return;
    float4 xv  = ((const float4*)X)[node * 8 + q];
    float4 acc = make_float4(0.f, 0.f, 0.f, 0.f);
#pragma unroll
    for (int k = 0; k < D; ++k) {
        float comp = (k & 3) == 0 ? xv.x : (k & 3) == 1 ? xv.y
                   : (k & 3) == 2 ? xv.z : xv.w;
        float  xk = __shfl(comp, k >> 2, 8);
        float4 wr = Ws[k * 8 + q];
        acc.x += xk * wr.x; acc.y += xk * wr.y;
        acc.z += xk * wr.z; acc.w += xk * wr.w;
    }
    ((float4*)H)[node * 8 + q] = acc;
}

__global__ void k_scan1(const int* __restrict__ cnt, int* __restrict__ bsum, int n) {
    __shared__ int s[BS];
    int t = threadIdx.x, i = blockIdx.x * BS + t;
    s[t] = (i < n) ? (cnt[i] - POISON_BASE) : 0;
    __syncthreads();
    for (int off = BS / 2; off > 0; off >>= 1) {
        if (t < off) s[t] += s[t + off];
        __syncthreads();
    }
    if (t == 0) bsum[blockIdx.x] = s[0];
}

__global__ void k_scan23(const int* __restrict__ cnt, const int* __restrict__ bsum,
                         int* __restrict__ rowptr, int n) {
    __shared__ int red[BS];
    __shared__ int s[BS];
    int t = threadIdx.x, i = blockIdx.x * BS + t;
    int pacc = 0;
    for (int k = t; k < (int)blockIdx.x; k += BS) pacc += bsum[k];
    red[t] = pacc;
    __syncthreads();
    for (int off = BS / 2; off > 0; off >>= 1) {
        if (t < off) red[t] += red[t + off];
        __syncthreads();
    }
    int bpre = red[0];
    int v = (i < n) ? (cnt[i] - POISON_BASE) : 0;
    s[t] = v;
    __syncthreads();
    for (int off = 1; off < BS; off <<= 1) {
        int u = (t >= off) ? s[t - off] : 0;
        __syncthreads();
        s[t] += u;
        __syncthreads();
    }
    if (i < n) {
        int excl = bpre + s[t] - v;
        rowptr[i] = excl;
        if (i == n - 1) rowptr[n] = excl + v;
    }
}

__global__ void k_reorder(const int4* __restrict__ src4, const int4* __restrict__ dst4,
                          const float4* __restrict__ w4, const int4* __restrict__ rank4,
                          const int* __restrict__ rowptr, int2* __restrict__ emeta, int E4) {
    int i = blockIdx.x * blockDim.x + threadIdx.x;
    if (i >= E4) return;
    int4   s = src4[i];
    int4   d = dst4[i];
    float4 w = w4[i];
    int4   r = rank4[i];
    emeta[rowptr[d.x] + r.x] = make_int2(s.x, __float_as_int(w.x));
    emeta[rowptr[d.y] + r.y] = make_int2(s.y, __float_as_int(w.y));
    emeta[rowptr[d.z] + r.z] = make_int2(s.z, __float_as_int(w.z));
    emeta[rowptr[d.w] + r.w] = make_int2(s.w, __float_as_int(w.w));
}

__global__ void k_degF(const int* __restrict__ rowptr, const int2* __restrict__ emeta,
                       float* __restrict__ dinv, int n) {
    int gid  = blockIdx.x * blockDim.x + threadIdx.x;
    int node = gid >> 3;
    int c    = gid & 7;
    if (node >= n) return;
    int beg = rowptr[node], end = rowptr[node + 1];
    float sum = 0.0f;
    for (int idx = beg + c; idx < end; idx += 8)
        sum += __int_as_float(emeta[idx].y);
    sum += __shfl_xor(sum, 4, 8);
    sum += __shfl_xor(sum, 2, 8);
    sum += __shfl_xor(sum, 1, 8);
    if (c == 0) dinv[node] = rsqrtf(2.0f + sum);
}

// ======== launch ========
extern "C" void kernel_launch(void* const* d_in, const int* in_sizes, int n_in,
                              void* d_out, int out_size, void* d_ws, size_t ws_size,
                              hipStream_t stream) {
    const float* x   = (const float*)d_in[0];
    const int*   ei  = (const int*)d_in[1];
    const float* w   = (const float*)d_in[2];
    const float* W1  = (const float*)d_in[3];
    const float* b1  = (const float*)d_in[4];
    const float* W2  = (const float*)d_in[5];
    const float* b2  = (const float*)d_in[6];
    float*       out = (float*)d_out;

    const int N = in_sizes[0] / D;       // 100000
    const int E = in_sizes[2];           // 1600000
    const int* src = ei;
    const int* dst = ei + E;

    const int NBUCK = (N + 63) / 64;                 // 1563
    const int EPB   = (E + CBLK - 1) / CBLK;         // 3200
    const int M     = NBUCK * CBLK;                  // 781500
    const int MA    = (M + BS - 1) / BS;             // 3053
    const int NB    = (N + BS - 1) / BS;
    const int E4    = E / 4;
    const int gE4   = (E4 + BS - 1) / BS;
    const int gN8   = (N * 8 + BS - 1) / BS;         // 3125

    // ---- workspace layout (all segments 16B-aligned; N*4 and E*8 are) ----
    char*  base   = (char*)d_ws;
    int2*  emeta  = (int2*)base;                                  // E*8
    float* ht     = (float*)(base + (size_t)E * 8);               // N*D*4
    float* ht2    = ht + (size_t)N * D;                           // N*D*4 (fused gemm2 out)
    float* dinv   = ht2 + (size_t)N * D;                          // N*4
    int*   rowptr = (int*)(dinv + N);                             // (N+4)&~3 ints
    int2*  staged = (int2*)(rowptr + ((N + 4) & ~3));             // E*8
    int*   bc     = (int*)(staged + E);                           // M ints (-> sc)
    int*   locoff = bc + ((M + 3) & ~3);                          // M ints
    int*   asum   = locoff + ((M + 3) & ~3);                      // MA ints
    int*   aex    = asum + ((MA + 3) & ~3);                       // MA ints
    size_t need   = (size_t)((char*)(aex + MA) - base);

    bool main_ok = (ws_size >= need) && (NBUCK <= MAXBUCK) && (N < (1 << 17)) &&
                   ((EPB + BS - 1) / BS <= MAX_EPT) && (EPB <= 8192);

    if (main_ok) {
        // ---- CSR build: all atomics in LDS; all global writes localized ----
        k_localsort_gemm<<<CBLK + gN8, BS, 0, stream>>>(dst, src, w, bc, locoff, staged,
                                                        E, EPB, NBUCK, x, W1, ht, N);
        k_scanA<<<MA, BS, 0, stream>>>(bc, asum, M);
        k_scanB<<<1, BS, 0, stream>>>(asum, aex, MA);
        k_scanC<<<MA, BS, 0, stream>>>(bc, aex, M);               // bc -> global positions
        k_merge<<<NBUCK, BS, 0, stream>>>(bc, locoff, staged, emeta, rowptr, dinv,
                                          N, E, NBUCK, EPB, M);
        // ---- layers: agg1 (+norm persist, relu) fused with gemm2 -> ht2; agg2 -> out ----
        k_aggregate<true,  true ><<<gN8, BS, 0, stream>>>(rowptr, emeta, ht,  dinv, b1, W2, ht2, N);
        k_aggregate<false, false><<<gN8, BS, 0, stream>>>(rowptr, emeta, ht2, dinv, b2, nullptr, out, N);
    } else {
        // ---- fallback: round-5 proven path ----
        int* cnt  = (int*)staged;             // N ints (start at POISON_BASE)
        int* rank = cnt + N;                  // E ints
        int* bsum = rank + E;                 // NB ints
        k_hist_gemm<<<gE4 + gN8, BS, 0, stream>>>((const int4*)dst, cnt, (int4*)rank, E4,
                                                  x, W1, ht, N, gE4);
        k_scan1 <<<NB, BS, 0, stream>>>(cnt, bsum, N);
        k_scan23<<<NB, BS, 0, stream>>>(cnt, bsum, rowptr, N);
        k_reorder<<<(E4 + BS - 1) / BS, BS, 0, stream>>>((const int4*)src, (const int4*)dst,
                                                         (const float4*)w, (const int4*)rank,
                                                         rowptr, emeta, E4);
        k_degF<<<gN8, BS, 0, stream>>>(rowptr, emeta, dinv, N);
        k_aggregate<true,  false><<<gN8, BS, 0, stream>>>(rowptr, emeta, ht, dinv, b1, nullptr, out, N);
        k_gemm<<<gN8, BS, 0, stream>>>(out, W2, ht, N);
        k_aggregate<false, false><<<gN8, BS, 0, stream>>>(rowptr, emeta, ht, dinv, b2, nullptr, out, N);
    }
}

// Round 11
// 225.860 us; speedup vs baseline: 1.0590x; 1.0590x over previous
//
#include <hip/hip_runtime.h>

#define D       32
#define BS      256
#define CBLK    500          // edge-chunk blocks for the local-sort pass
#define MAXBUCK 2048         // LDS histogram capacity (NBUCK = ceil(N/64) must fit)
#define MAX_EPT 13           // max edges per thread in local sort (ceil(EPB/BS))
#define ECAP    4096         // LDS edge-buffer capacity in k_merge (bucket size)
#define POISON_BASE ((int)0xAAAAAAAAu)

// ---- bf16 helpers: feature tables stored as bf16 (64 B/row), math in fp32 ----
__device__ inline unsigned bf16pack2(float a, float b) {
    unsigned ua = __float_as_uint(a);
    unsigned ub = __float_as_uint(b);
    ua = (ua + 0x7FFFu + ((ua >> 16) & 1)) >> 16;   // RNE
    ub = (ub + 0x7FFFu + ((ub >> 16) & 1)) >> 16;
    return ua | (ub << 16);
}
__device__ inline uint2 bf16pack4(float4 v) {
    return make_uint2(bf16pack2(v.x, v.y), bf16pack2(v.z, v.w));
}
__device__ inline float4 bf16unpack4(uint2 h) {
    return make_float4(__uint_as_float(h.x << 16),
                       __uint_as_float(h.x & 0xFFFF0000u),
                       __uint_as_float(h.y << 16),
                       __uint_as_float(h.y & 0xFFFF0000u));
}

// ======== pass 1: block-local counting sort (+ fused layer-1 GEMM -> bf16 ht) ========
__global__ void k_localsort_gemm(const int* __restrict__ dst, const int* __restrict__ src,
                                 const float* __restrict__ w, int* __restrict__ bc,
                                 int* __restrict__ locoff, int2* __restrict__ staged,
                                 int E, int EPB, int NBUCK,
                                 const float* __restrict__ X, const float* __restrict__ Wm,
                                 uint2* __restrict__ H, int n) {
    __shared__ int    bins[MAXBUCK];
    __shared__ int    sscan[BS];
    __shared__ int    carry;
    __shared__ float4 Ws[D * 8];
    int t = threadIdx.x;

    if ((int)blockIdx.x >= CBLK) {
        // ---- gemm1: H = X @ W1 (8 lanes/node; fp32 in, bf16 out) ----
        for (int i = t; i < D * 8; i += BS) Ws[i] = ((const float4*)Wm)[i];
        __syncthreads();
        int gid  = (blockIdx.x - CBLK) * BS + t;
        int node = gid >> 3;
        int q    = gid & 7;
        if (node >= n) return;
        float4 xv  = ((const float4*)X)[node * 8 + q];
        float4 acc = make_float4(0.f, 0.f, 0.f, 0.f);
#pragma unroll
        for (int k = 0; k < D; ++k) {
            float comp = (k & 3) == 0 ? xv.x : (k & 3) == 1 ? xv.y
                       : (k & 3) == 2 ? xv.z : xv.w;
            float  xk = __shfl(comp, k >> 2, 8);
            float4 wr = Ws[k * 8 + q];
            acc.x += xk * wr.x; acc.y += xk * wr.y;
            acc.z += xk * wr.z; acc.w += xk * wr.w;
        }
        H[node * 8 + q] = bf16pack4(acc);
        return;
    }

    int blk = blockIdx.x;
    int beg = blk * EPB;
    int end = min(E, beg + EPB);
    for (int i = t; i < NBUCK; i += BS) bins[i] = 0;
    __syncthreads();

    // loop 1: histogram; stash (bucket<<19 | local<<13 | rank)
    int stash[MAX_EPT];
#pragma unroll
    for (int i = 0; i < MAX_EPT; ++i) {
        int e = beg + i * BS + t;
        stash[i] = -1;
        if (e < end) {
            int dv = dst[e];
            int b  = dv >> 6;
            int r  = atomicAdd(&bins[b], 1);        // LDS atomic; r < EPB <= 8192
            stash[i] = (b << 19) | ((dv & 63) << 13) | r;
        }
    }
    __syncthreads();
    for (int i = t; i < NBUCK; i += BS) bc[i * CBLK + blk] = bins[i];
    __syncthreads();
    // chunked exclusive scan of bins in place
    if (t == 0) carry = 0;
    __syncthreads();
    for (int base = 0; base < NBUCK; base += BS) {
        int idx = base + t;
        int v = (idx < NBUCK) ? bins[idx] : 0;
        sscan[t] = v;
        __syncthreads();
        for (int off = 1; off < BS; off <<= 1) {
            int u = (t >= off) ? sscan[t - off] : 0;
            __syncthreads();
            sscan[t] += u;
            __syncthreads();
        }
        if (idx < NBUCK) bins[idx] = carry + sscan[t] - v;
        __syncthreads();
        if (t == 0) carry += sscan[BS - 1];
        __syncthreads();
    }
    for (int i = t; i < NBUCK; i += BS) locoff[i * CBLK + blk] = bins[i];
    __syncthreads();

    // loop 2: place edges into own staging slice
    int2* myslice = staged + (size_t)blk * EPB;
#pragma unroll
    for (int i = 0; i < MAX_EPT; ++i) {
        if (stash[i] >= 0) {
            int e     = beg + i * BS + t;
            int b     = stash[i] >> 19;
            int local = (stash[i] >> 13) & 63;
            int r     = stash[i] & 0x1FFF;
            int pos   = bins[b] + r;
            myslice[pos] = make_int2(src[e] | (local << 17), __float_as_int(w[e]));
        }
    }
}

// ======== scans over the (bucket-major) count table ========
__global__ void k_scanA(const int* __restrict__ bc, int* __restrict__ asum, int m) {
    __shared__ int s[BS];
    int t = threadIdx.x, i = blockIdx.x * BS + t;
    s[t] = (i < m) ? bc[i] : 0;
    __syncthreads();
    for (int off = BS / 2; off > 0; off >>= 1) {
        if (t < off) s[t] += s[t + off];
        __syncthreads();
    }
    if (t == 0) asum[blockIdx.x] = s[0];
}

__global__ void k_scanB(const int* __restrict__ asum, int* __restrict__ aex, int m) {
    __shared__ int s[BS];
    __shared__ int carry;
    int t = threadIdx.x;
    if (t == 0) carry = 0;
    __syncthreads();
    for (int base = 0; base < m; base += BS) {
        int i = base + t;
        int v = (i < m) ? asum[i] : 0;
        s[t] = v;
        __syncthreads();
        for (int off = 1; off < BS; off <<= 1) {
            int u = (t >= off) ? s[t - off] : 0;
            __syncthreads();
            s[t] += u;
            __syncthreads();
        }
        if (i < m) aex[i] = carry + s[t] - v;
        __syncthreads();
        if (t == BS - 1) carry += s[BS - 1];
        __syncthreads();
    }
}

__global__ void k_scanC(int* __restrict__ bc, const int* __restrict__ aex, int m) {
    __shared__ int s[BS];
    int t = threadIdx.x, i = blockIdx.x * BS + t;
    int v = (i < m) ? bc[i] : 0;
    s[t] = v;
    __syncthreads();
    for (int off = 1; off < BS; off <<= 1) {
        int u = (t >= off) ? s[t - off] : 0;
        __syncthreads();
        s[t] += u;
        __syncthreads();
    }
    if (i < m) bc[i] = aex[blockIdx.x] + s[t] - v;   // -> global positions sc[]
}

// ======== pass 3: per-bucket merge -> fine CSR + dinv + emeta ========
__global__ void k_merge(const int* __restrict__ sc, const int* __restrict__ locoff,
                        const int2* __restrict__ staged, int2* __restrict__ emeta,
                        int* __restrict__ rowptr, float* __restrict__ dinv,
                        int N, int E, int NBUCK, int EPB, int M) {
    __shared__ int2  ebuf[ECAP];
    __shared__ int   ihist[64];
    __shared__ float fdeg[64];
    __shared__ int   cursor[64];
    __shared__ int   fitsf;
    int b = blockIdx.x, t = threadIdx.x;
    int bstart = sc[b * CBLK];
    int bend   = (b == NBUCK - 1) ? E : sc[(b + 1) * CBLK];
    if (t < 64) { ihist[t] = 0; fdeg[t] = 0.0f; }
    if (t == 0) fitsf = (bend - bstart) <= ECAP;
    __syncthreads();
    bool fits = fitsf;

    for (int rr = t; rr < CBLK; rr += BS) {
        int cell = b * CBLK + rr;
        int gs = sc[cell];
        int ge = (cell + 1 < M) ? sc[cell + 1] : E;
        int ls = locoff[cell];
        const int2* run = staged + (size_t)rr * EPB + ls;
        for (int j = 0; j < ge - gs; ++j) {
            int2 v = run[j];
            int local = (v.x >> 17) & 63;
            atomicAdd(&ihist[local], 1);
            atomicAdd(&fdeg[local], __int_as_float(v.y));
            if (fits) ebuf[gs - bstart + j] = v;
        }
    }
    __syncthreads();
    if (t < 64) {
        int v = ihist[t];
        int incl = v;
#pragma unroll
        for (int off = 1; off < 64; off <<= 1) {
            int u = __shfl_up(incl, off, 64);
            if (t >= off) incl += u;
        }
        int excl = incl - v;
        int node = b * 64 + t;
        if (node < N) {
            rowptr[node] = bstart + excl;
            dinv[node]   = rsqrtf(2.0f + fdeg[t]);
        }
        if (b == NBUCK - 1 && t == 0) rowptr[N] = E;
        cursor[t] = excl;
    }
    __syncthreads();
    for (int rr = t; rr < CBLK; rr += BS) {
        int cell = b * CBLK + rr;
        int gs = sc[cell];
        int ge = (cell + 1 < M) ? sc[cell + 1] : E;
        int ls = locoff[cell];
        const int2* run = staged + (size_t)rr * EPB + ls;
        for (int j = 0; j < ge - gs; ++j) {
            int2 v = fits ? ebuf[gs - bstart + j] : run[j];
            int local = (v.x >> 17) & 63;
            int r = atomicAdd(&cursor[local], 1);
            emeta[bstart + r] = make_int2(v.x & 0x1FFFF, v.y);
        }
    }
}

// ======== layers (feature tables in bf16, math in fp32) ========

// standalone gemm (fallback layer 2): fp32 in -> bf16 table out
__global__ void k_gemm(const float* __restrict__ X, const float* __restrict__ W,
                       uint2* __restrict__ H, int n) {
    __shared__ float4 Ws[D * 8];
    int tid = threadIdx.x;
    for (int i = tid; i < D * 8; i += blockDim.x) Ws[i] = ((const float4*)W)[i];
    __syncthreads();
    int gid  = blockIdx.x * blockDim.x + tid;
    int node = gid >> 3;
    int q    = gid & 7;
    if (node >= n) return;
    float4 xv  = ((const float4*)X)[node * 8 + q];
    float4 acc = make_float4(0.f, 0.f, 0.f, 0.f);
#pragma unroll
    for (int k = 0; k < D; ++k) {
        float comp = (k & 3) == 0 ? xv.x : (k & 3) == 1 ? xv.y
                   : (k & 3) == 2 ? xv.z : xv.w;
        float  xk = __shfl(comp, k >> 2, 8);
        float4 wr = Ws[k * 8 + q];
        acc.x += xk * wr.x; acc.y += xk * wr.y;
        acc.z += xk * wr.z; acc.w += xk * wr.w;
    }
    H[node * 8 + q] = bf16pack4(acc);
}

// NORM_STORE: emeta.y raw w -> nm = dinv[s]*w*dinv[d], persisted.
// FUSE_GEMM: out_bf16 = (relu(agg) @ W2) packed bf16; else out_f32 = relu(agg).
template <bool NORM_STORE, bool FUSE_GEMM>
__global__ void k_aggregate(const int* __restrict__ rowptr, int2* __restrict__ emeta,
                            const uint2* __restrict__ H, const float* __restrict__ dinv,
                            const float* __restrict__ b, const float* __restrict__ W2,
                            void* __restrict__ outv, int n) {
    __shared__ float4 Ws[D * 8];
    int tid = threadIdx.x;
    if (FUSE_GEMM) {
        for (int i = tid; i < D * 8; i += BS) Ws[i] = ((const float4*)W2)[i];
        __syncthreads();
    }

    int gid  = blockIdx.x * BS + tid;
    int node = gid >> 3;
    int q    = gid & 7;
    if (node >= n) return;

    float  di = dinv[node];
    float  s2 = 2.0f * di * di;
    float4 bq = ((const float4*)b)[q];
    float4 h0 = bf16unpack4(H[node * 8 + q]);
    float4 acc = make_float4(h0.x * s2 + bq.x, h0.y * s2 + bq.y,
                             h0.z * s2 + bq.z, h0.w * s2 + bq.w);

    int beg  = rowptr[node];
    int end  = rowptr[node + 1];
    int full = beg + ((end - beg) & ~7);

    for (int i0 = beg; i0 < full; i0 += 8) {
        int  idx = i0 + q;
        int2 em  = emeta[idx];
        float nm;
        if (NORM_STORE) {
            nm = dinv[em.x] * __int_as_float(em.y) * di;
            emeta[idx].y = __float_as_int(nm);
        } else {
            nm = __int_as_float(em.y);
        }
#pragma unroll
        for (int j = 0; j < 8; ++j) {
            int    s   = __shfl(em.x, j, 8);
            float  nmj = __shfl(nm, j, 8);
            float4 hv  = bf16unpack4(H[s * 8 + q]);      // 8 lanes -> 64B coalesced
            acc.x += nmj * hv.x; acc.y += nmj * hv.y;
            acc.z += nmj * hv.z; acc.w += nmj * hv.w;
        }
    }
    if (full < end) {
        int  idx = full + q;
        bool ok  = idx < end;
        int2 em  = ok ? emeta[idx] : make_int2(0, 0);
        float nm;
        if (NORM_STORE) {
            nm = ok ? dinv[em.x] * __int_as_float(em.y) * di : 0.0f;
            if (ok) emeta[idx].y = __float_as_int(nm);
        } else {
            nm = __int_as_float(em.y);
        }
        int rem = end - full;
        for (int j = 0; j < rem; ++j) {
            int    s   = __shfl(em.x, j, 8);
            float  nmj = __shfl(nm, j, 8);
            float4 hv  = bf16unpack4(H[s * 8 + q]);
            acc.x += nmj * hv.x; acc.y += nmj * hv.y;
            acc.z += nmj * hv.z; acc.w += nmj * hv.w;
        }
    }
    acc.x = fmaxf(acc.x, 0.f); acc.y = fmaxf(acc.y, 0.f);
    acc.z = fmaxf(acc.z, 0.f); acc.w = fmaxf(acc.w, 0.f);

    if (FUSE_GEMM) {
        float4 o = make_float4(0.f, 0.f, 0.f, 0.f);
#pragma unroll
        for (int k = 0; k < D; ++k) {
            float comp = (k & 3) == 0 ? acc.x : (k & 3) == 1 ? acc.y
                       : (k & 3) == 2 ? acc.z : acc.w;
            float  hk = __shfl(comp, k >> 2, 8);
            float4 wr = Ws[k * 8 + q];
            o.x += hk * wr.x; o.y += hk * wr.y;
            o.z += hk * wr.z; o.w += hk * wr.w;
        }
        ((uint2*)outv)[node * 8 + q] = bf16pack4(o);
    } else {
        ((float4*)outv)[node * 8 + q] = acc;
    }
}

// ======== fallback path (global-atomic hist; bf16 tables) ========
__global__ void k_hist_gemm(const int4* __restrict__ dst4, int* __restrict__ cnt,
                            int4* __restrict__ rank4, int E4,
                            const float* __restrict__ X, const float* __restrict__ W,
                            uint2* __restrict__ H, int n, int gE4) {
    __shared__ float4 Ws[D * 8];
    int tid = threadIdx.x;
    if ((int)blockIdx.x < gE4) {
        int i = blockIdx.x * BS + tid;
        if (i >= E4) return;
        int4 d = dst4[i];
        int4 r;
        r.x = atomicAdd(&cnt[d.x], 1) - POISON_BASE;
        r.y = atomicAdd(&cnt[d.y], 1) - POISON_BASE;
        r.z = atomicAdd(&cnt[d.z], 1) - POISON_BASE;
        r.w = atomicAdd(&cnt[d.w], 1) - POISON_BASE;
        rank4[i] = r;
        return;
    }
    for (int i = tid; i < D * 8; i += BS) Ws[i] = ((const float4*)W)[i];
    __syncthreads();
    int gid  = (blockIdx.x - gE4) * BS + tid;
    int node = gid >> 3;
    int q    = gid & 7;
    if (node >= n) return;
    float4 xv  = ((const float4*)X)[node * 8 + q];
    float4 acc = make_float4(0.f, 0.f, 0.f, 0.f);
#pragma unroll
    for (int k = 0; k < D; ++k) {
        float comp = (k & 3) == 0 ? xv.x : (k & 3) == 1 ? xv.y
                   : (k & 3) == 2 ? xv.z : xv.w;
        float  xk = __shfl(comp, k >> 2, 8);
        float4 wr = Ws[k * 8 + q];
        acc.x += xk * wr.x; acc.y += xk * wr.y;
        acc.z += xk * wr.z; acc.w += xk * wr.w;
    }
    H[node * 8 + q] = bf16pack4(acc);
}

__global__ void k_scan1(const int* __restrict__ cnt, int* __restrict__ bsum, int n) {
    __shared__ int s[BS];
    int t = threadIdx.x, i = blockIdx.x * BS + t;
    s[t] = (i < n) ? (cnt[i] - POISON_BASE) : 0;
    __syncthreads();
    for (int off = BS / 2; off > 0; off >>= 1) {
        if (t < off) s[t] += s[t + off];
        __syncthreads();
    }
    if (t == 0) bsum[blockIdx.x] = s[0];
}

__global__ void k_scan23(const int* __restrict__ cnt, const int* __restrict__ bsum,
                         int* __restrict__ rowptr, int n) {
    __shared__ int red[BS];
    __shared__ int s[BS];
    int t = threadIdx.x, i = blockIdx.x * BS + t;
    int pacc = 0;
    for (int k = t; k < (int)blockIdx.x; k += BS) pacc += bsum[k];
    red[t] = pacc;
    __syncthreads();
    for (int off = BS / 2; off > 0; off >>= 1) {
        if (t < off) red[t] += red[t + off];
        __syncthreads();
    }
    int bpre = red[0];
    int v = (i < n) ? (cnt[i] - POISON_BASE) : 0;
    s[t] = v;
    __syncthreads();
    for (int off = 1; off < BS; off <<= 1) {
        int u = (t >= off) ? s[t - off] : 0;
        __syncthreads();
        s[t] += u;
        __syncthreads();
    }
    if (i < n) {
        int excl = bpre + s[t] - v;
        rowptr[i] = excl;
        if (i == n - 1) rowptr[n] = excl + v;
    }
}

__global__ void k_reorder(const int4* __restrict__ src4, const int4* __restrict__ dst4,
                          const float4* __restrict__ w4, const int4* __restrict__ rank4,
                          const int* __restrict__ rowptr, int2* __restrict__ emeta, int E4) {
    int i = blockIdx.x * blockDim.x + threadIdx.x;
    if (i >= E4) return;
    int4   s = src4[i];
    int4   d = dst4[i];
    float4 w = w4[i];
    int4   r = rank4[i];
    emeta[rowptr[d.x] + r.x] = make_int2(s.x, __float_as_int(w.x));
    emeta[rowptr[d.y] + r.y] = make_int2(s.y, __float_as_int(w.y));
    emeta[rowptr[d.z] + r.z] = make_int2(s.z, __float_as_int(w.z));
    emeta[rowptr[d.w] + r.w] = make_int2(s.w, __float_as_int(w.w));
}

__global__ void k_degF(const int* __restrict__ rowptr, const int2* __restrict__ emeta,
                       float* __restrict__ dinv, int n) {
    int gid  = blockIdx.x * blockDim.x + threadIdx.x;
    int node = gid >> 3;
    int c    = gid & 7;
    if (node >= n) return;
    int beg = rowptr[node], end = rowptr[node + 1];
    float sum = 0.0f;
    for (int idx = beg + c; idx < end; idx += 8)
        sum += __int_as_float(emeta[idx].y);
    sum += __shfl_xor(sum, 4, 8);
    sum += __shfl_xor(sum, 2, 8);
    sum += __shfl_xor(sum, 1, 8);
    if (c == 0) dinv[node] = rsqrtf(2.0f + sum);
}

// ======== launch ========
extern "C" void kernel_launch(void* const* d_in, const int* in_sizes, int n_in,
                              void* d_out, int out_size, void* d_ws, size_t ws_size,
                              hipStream_t stream) {
    const float* x   = (const float*)d_in[0];
    const int*   ei  = (const int*)d_in[1];
    const float* w   = (const float*)d_in[2];
    const float* W1  = (const float*)d_in[3];
    const float* b1  = (const float*)d_in[4];
    const float* W2  = (const float*)d_in[5];
    const float* b2  = (const float*)d_in[6];
    float*       out = (float*)d_out;

    const int N = in_sizes[0] / D;       // 100000
    const int E = in_sizes[2];           // 1600000
    const int* src = ei;
    const int* dst = ei + E;

    const int NBUCK = (N + 63) / 64;                 // 1563
    const int EPB   = (E + CBLK - 1) / CBLK;         // 3200
    const int M     = NBUCK * CBLK;                  // 781500
    const int MA    = (M + BS - 1) / BS;             // 3053
    const int NB    = (N + BS - 1) / BS;
    const int E4    = E / 4;
    const int gE4   = (E4 + BS - 1) / BS;
    const int gN8   = (N * 8 + BS - 1) / BS;         // 3125

    // ---- workspace layout (all segments 16B-aligned) ----
    char*  base   = (char*)d_ws;
    int2*  emeta  = (int2*)base;                                  // E*8
    uint2* ht     = (uint2*)(base + (size_t)E * 8);               // N*D*2 (bf16)
    uint2* ht2    = ht + (size_t)N * 8;                           // N*D*2 (bf16)
    float* dinv   = (float*)(ht2 + (size_t)N * 8);                // N*4
    int*   rowptr = (int*)(dinv + N);                             // (N+4)&~3 ints
    int2*  staged = (int2*)(rowptr + ((N + 4) & ~3));             // E*8
    int*   bc     = (int*)(staged + E);                           // M ints (-> sc)
    int*   locoff = bc + ((M + 3) & ~3);                          // M ints
    int*   asum   = locoff + ((M + 3) & ~3);                      // MA ints
    int*   aex    = asum + ((MA + 3) & ~3);                       // MA ints
    size_t need   = (size_t)((char*)(aex + MA) - base);

    bool main_ok = (ws_size >= need) && (NBUCK <= MAXBUCK) && (N < (1 << 17)) &&
                   ((EPB + BS - 1) / BS <= MAX_EPT) && (EPB <= 8192) && (N % 4 == 0);

    if (main_ok) {
        // ---- CSR build: all atomics in LDS; all global writes localized ----
        k_localsort_gemm<<<CBLK + gN8, BS, 0, stream>>>(dst, src, w, bc, locoff, staged,
                                                        E, EPB, NBUCK, x, W1, ht, N);
        k_scanA<<<MA, BS, 0, stream>>>(bc, asum, M);
        k_scanB<<<1, BS, 0, stream>>>(asum, aex, MA);
        k_scanC<<<MA, BS, 0, stream>>>(bc, aex, M);               // bc -> global positions
        k_merge<<<NBUCK, BS, 0, stream>>>(bc, locoff, staged, emeta, rowptr, dinv,
                                          N, E, NBUCK, EPB, M);
        // ---- layers: agg1 (+norm persist, relu) fused w/ gemm2 -> bf16 ht2; agg2 -> fp32 out ----
        k_aggregate<true,  true ><<<gN8, BS, 0, stream>>>(rowptr, emeta, ht,  dinv, b1, W2, ht2, N);
        k_aggregate<false, false><<<gN8, BS, 0, stream>>>(rowptr, emeta, ht2, dinv, b2, nullptr, out, N);
    } else {
        // ---- fallback: global-atomic hist path ----
        int* cnt  = (int*)staged;             // N ints (start at POISON_BASE)
        int* rank = cnt + N;                  // E ints
        int* bsum = rank + E;                 // NB ints
        k_hist_gemm<<<gE4 + gN8, BS, 0, stream>>>((const int4*)dst, cnt, (int4*)rank, E4,
                                                  x, W1, ht, N, gE4);
        k_scan1 <<<NB, BS, 0, stream>>>(cnt, bsum, N);
        k_scan23<<<NB, BS, 0, stream>>>(cnt, bsum, rowptr, N);
        k_reorder<<<(E4 + BS - 1) / BS, BS, 0, stream>>>((const int4*)src, (const int4*)dst,
                                                         (const float4*)w, (const int4*)rank,
                                                         rowptr, emeta, E4);
        k_degF<<<gN8, BS, 0, stream>>>(rowptr, emeta, dinv, N);
        k_aggregate<true,  false><<<gN8, BS, 0, stream>>>(rowptr, emeta, ht, dinv, b1, nullptr, out, N);
        k_gemm<<<gN8, BS, 0, stream>>>(out, W2, ht, N);
        k_aggregate<false, false><<<gN8, BS, 0, stream>>>(rowptr, emeta, ht, dinv, b2, nullptr, out, N);
    }
}